// Round 1
// baseline (632.399 us; speedup 1.0000x reference)
//
#include <hip/hip_runtime.h>

// CRF Viterbi decode (B=512, T=512, S=64).
// One wave (64 threads) per batch element; lane n = next-tag.
// Forward: 511 steps, argmax over prev via 8 contiguous chains + ordered
// tree-merge (exact jnp.argmax first-max semantics). Backpointers packed
// 4 tags/dword into LDS (32 KB/block). Backtrace: readlane chain (tag is
// wave-uniform SGPR), emits tags into LDS, coalesced copy out.
// Output: out[0..B) = path_score, out[B + b*(T-1) + t] = (float)tag.

constexpr int Bz = 512;
constexpr int Tz = 512;
constexpr int Sz = 64;
constexpr float NEGINF = -10000.0f;

__device__ __forceinline__ float rlf(float x, int lane) {
    return __int_as_float(__builtin_amdgcn_readlane(__float_as_int(x), lane));
}

__global__ __launch_bounds__(64)
void crf_viterbi_kernel(const float* __restrict__ logits,
                        const float* __restrict__ masks,
                        const float* __restrict__ trans,
                        float* __restrict__ out)
{
    const int n = threadIdx.x;   // next-tag index / lane id
    const int b = blockIdx.x;

    __shared__ unsigned bp[128 * 64];   // packed backpointers [group][lane], 32 KB
    __shared__ float ys[Tz - 1];        // emitted tags (backtrace)

    // --- transitions row n into registers (16 x float4) ---
    float tr[64];
    const float4* tr4 = reinterpret_cast<const float4*>(trans + n * 64);
    #pragma unroll
    for (int k = 0; k < 16; ++k) {
        float4 v = tr4[k];
        tr[4 * k + 0] = v.x;
        tr[4 * k + 1] = v.y;
        tr[4 * k + 2] = v.z;
        tr[4 * k + 3] = v.w;
    }

    // init: fv[0] = 0, else NEG_INF
    float fv = (n == 0) ? 0.0f : NEGINF;

    const float* lgbase = logits + (size_t)b * Tz * Sz;
    const float* mkbase = masks + (size_t)b * Tz;

    float lg_next = lgbase[1 * Sz + n];   // emission for step 0 (t=1)
    unsigned pk = 0;
    float psc = 0.0f;

    for (int i = 0; i < Tz - 1; ++i) {
        float lg = lg_next;
        int t2 = (i + 2 < Tz) ? (i + 2) : (Tz - 1);
        lg_next = lgbase[t2 * Sz + n];          // prefetch next emission
        float mk = mkbase[i + 1];               // wave-uniform -> s_load

        // 8 contiguous chains of 8 (strict > keeps FIRST max within chain)
        float mv[8];
        int   mi[8];
        #pragma unroll
        for (int c = 0; c < 8; ++c) {
            int p0 = 8 * c;
            mv[c] = rlf(fv, p0) + tr[p0];
            mi[c] = p0;
            #pragma unroll
            for (int j = 1; j < 8; ++j) {
                int p = p0 + j;
                float v = rlf(fv, p) + tr[p];
                bool gt = v > mv[c];
                mi[c] = gt ? p : mi[c];
                mv[c] = gt ? v : mv[c];
            }
        }
        // ordered tree merge: left operand always holds lower indices,
        // strict > keeps left on ties -> exact first-max semantics
        #pragma unroll
        for (int st = 1; st < 8; st <<= 1) {
            #pragma unroll
            for (int c = 0; c < 8; c += 2 * st) {
                bool gt = mv[c + st] > mv[c];
                mi[c] = gt ? mi[c + st] : mi[c];
                mv[c] = gt ? mv[c + st] : mv[c];
            }
        }
        float maxv = mv[0];
        int   maxi = mi[0];

        if (i == Tz - 2) psc = maxv;            // vmaxs[-1] pre-feat

        pk |= ((unsigned)maxi) << (8 * (i & 3));
        if ((i & 3) == 3) {
            bp[(i >> 2) * 64 + n] = pk;
            pk = 0;
        }
        fv = maxv + lg * mk;                    // mask multiplies emission only
    }
    bp[127 * 64 + n] = pk;                       // flush steps 508..510

    if (n == 63) out[b] = psc;                   // path_score = vmaxs[-1][:,63]

    __syncthreads();

    // --- backtrace ---
    unsigned wcur = bp[127 * 64 + n];
    int w127_63 = __builtin_amdgcn_readlane((int)wcur, 63);
    int tag = (w127_63 >> 16) & 255;             // t0 = bptrs[510][63]

    for (int g = 127; g >= 0; --g) {
        unsigned wnext = (g > 0) ? bp[(g - 1) * 64 + n] : 0u;  // prefetch
        int smax = (g == 127) ? 2 : 3;
        for (int s = smax; s >= 0; --s) {
            int i = 4 * g + s;
            if (n == 0) ys[i] = (float)tag;      // emit BEFORE following ptr
            int w = __builtin_amdgcn_readlane((int)wcur, tag);
            tag = (w >> (8 * s)) & 255;
        }
        wcur = wnext;
    }

    __syncthreads();

    float* outseq = out + Bz + (size_t)b * (Tz - 1);
    for (int k = n; k < Tz - 1; k += 64) outseq[k] = ys[k];
}

extern "C" void kernel_launch(void* const* d_in, const int* in_sizes, int n_in,
                              void* d_out, int out_size, void* d_ws, size_t ws_size,
                              hipStream_t stream) {
    const float* logits = (const float*)d_in[0];
    const float* masks  = (const float*)d_in[1];
    const float* trans  = (const float*)d_in[2];
    float* out = (float*)d_out;
    (void)in_sizes; (void)n_in; (void)out_size; (void)d_ws; (void)ws_size;

    crf_viterbi_kernel<<<dim3(Bz), dim3(64), 0, stream>>>(logits, masks, trans, out);
}

// Round 3
// 414.286 us; speedup vs baseline: 1.5265x; 1.5265x over previous
//
#include <hip/hip_runtime.h>

// CRF Viterbi decode (B=512, T=512, S=64).
// R2: 4 waves per block (256 thr), one batch per block. Wave w owns prev
// range [16w, 16w+16); lane n = next-tag. Per step each wave computes a
// partial (first-)argmax over its 16 prevs, waves exchange partials via
// double-buffered LDS (1 barrier/step), and every wave redundantly merges
// the 4 partials so the new fv vector lives in all waves' registers
// (next step's fv gather is an in-wave readlane -> no second barrier).
// Backpointers packed 4 tags/dword in LDS (32 KB). Backtrace: wave 0,
// readlane chain as in R1 (validated bit-exact).
// Output: out[0..B) = path_score, out[B + b*(T-1) + t] = (float)tag.

constexpr int Bz = 512;
constexpr int Tz = 512;
constexpr int Sz = 64;
constexpr float NEGINF = -10000.0f;

__device__ __forceinline__ float rlf(float x, int lane) {
    return __int_as_float(__builtin_amdgcn_readlane(__float_as_int(x), lane));
}

__global__ __launch_bounds__(256)
void crf_viterbi_kernel(const float* __restrict__ logits,
                        const float* __restrict__ masks,
                        const float* __restrict__ trans,
                        float* __restrict__ out)
{
    const int n = threadIdx.x & 63;   // next-tag index / lane id
    const int w = threadIdx.x >> 6;   // wave id = prev-range selector
    const int b = blockIdx.x;
    const int pbase = w * 16;         // first prev this wave owns

    __shared__ unsigned bp[128 * 64];     // packed backpointers, 32 KB
    __shared__ float pval[2][4][64];      // per-wave partial max values
    __shared__ int   pidx[2][4][64];      // per-wave partial argmax (global prev)
    __shared__ float ys[Tz - 1];          // emitted tags (backtrace)

    // --- transitions tr[n][pbase..pbase+16) into registers (4 x float4) ---
    float tr[16];
    const float4* tr4 = reinterpret_cast<const float4*>(trans + n * 64 + pbase);
    #pragma unroll
    for (int k = 0; k < 4; ++k) {
        float4 v = tr4[k];
        tr[4 * k + 0] = v.x;
        tr[4 * k + 1] = v.y;
        tr[4 * k + 2] = v.z;
        tr[4 * k + 3] = v.w;
    }

    // init: fv[0] = 0, else NEG_INF (replicated in every wave; lane n = tag n)
    float fv = (n == 0) ? 0.0f : NEGINF;

    const float* lgbase = logits + (size_t)b * Tz * Sz;
    const float* mkbase = masks + (size_t)b * Tz;

    float lg_next = lgbase[1 * Sz + n];   // emission for step 0 (t=1)
    unsigned pk = 0;
    float psc = 0.0f;

    #pragma unroll 4
    for (int i = 0; i < Tz - 1; ++i) {
        float lg = lg_next;
        int t2 = (i + 2 < Tz) ? (i + 2) : (Tz - 1);
        lg_next = lgbase[t2 * Sz + n];          // prefetch next emission
        float mk = mkbase[i + 1];               // wave-uniform load

        // gather fv[pbase+j] (in-wave cross-lane) and form 16 scores
        float v[16];
        #pragma unroll
        for (int j = 0; j < 16; ++j)
            v[j] = rlf(fv, pbase + j) + tr[j];

        // 2 contiguous chains of 8 (strict > keeps FIRST max within chain)
        float mv[2];
        int   mi[2];
        #pragma unroll
        for (int c = 0; c < 2; ++c) {
            int p0 = 8 * c;
            mv[c] = v[p0];
            mi[c] = pbase + p0;
            #pragma unroll
            for (int j = 1; j < 8; ++j) {
                float x = v[p0 + j];
                bool gt = x > mv[c];
                mi[c] = gt ? (pbase + p0 + j) : mi[c];
                mv[c] = gt ? x : mv[c];
            }
        }
        // ordered merge (left = lower prevs, strict > keeps left on ties)
        {
            bool gt = mv[1] > mv[0];
            mi[0] = gt ? mi[1] : mi[0];
            mv[0] = gt ? mv[1] : mv[0];
        }

        // publish partial, one barrier, redundant 4-way ordered combine
        const int buf = i & 1;
        pval[buf][w][n] = mv[0];
        pidx[buf][w][n] = mi[0];
        __syncthreads();

        float c0 = pval[buf][0][n], c1 = pval[buf][1][n];
        float c2 = pval[buf][2][n], c3 = pval[buf][3][n];
        int   j0 = pidx[buf][0][n], j1 = pidx[buf][1][n];
        int   j2 = pidx[buf][2][n], j3 = pidx[buf][3][n];

        bool g1 = c1 > c0;  float m01 = g1 ? c1 : c0;  int k01 = g1 ? j1 : j0;
        bool g3 = c3 > c2;  float m23 = g3 ? c3 : c2;  int k23 = g3 ? j3 : j2;
        bool gm = m23 > m01;
        float maxv = gm ? m23 : m01;
        int   maxi = gm ? k23 : k01;

        if (i == Tz - 2) psc = maxv;            // vmaxs[-1] pre-feat

        if (w == 0) {
            pk |= ((unsigned)maxi) << (8 * (i & 3));
            if ((i & 3) == 3) {
                bp[(i >> 2) * 64 + n] = pk;
                pk = 0;
            }
        }
        fv = maxv + lg * mk;                    // mask multiplies emission only
    }
    if (w == 0) bp[127 * 64 + n] = pk;          // flush steps 508..510
    if (w == 0 && n == 63) out[b] = psc;        // path_score = vmaxs[-1][:,63]

    __syncthreads();

    // --- backtrace (wave 0 only; identical to validated R1 code) ---
    if (w == 0) {
        unsigned wcur = bp[127 * 64 + n];
        int w127_63 = __builtin_amdgcn_readlane((int)wcur, 63);
        int tag = (w127_63 >> 16) & 255;        // t0 = bptrs[510][63]

        for (int g = 127; g >= 0; --g) {
            unsigned wnext = (g > 0) ? bp[(g - 1) * 64 + n] : 0u;  // prefetch
            int smax = (g == 127) ? 2 : 3;
            for (int s = smax; s >= 0; --s) {
                int idx = 4 * g + s;
                if (n == 0) ys[idx] = (float)tag;   // emit BEFORE following ptr
                int wd = __builtin_amdgcn_readlane((int)wcur, tag);
                tag = (wd >> (8 * s)) & 255;
            }
            wcur = wnext;
        }
    }

    __syncthreads();

    float* outseq = out + Bz + (size_t)b * (Tz - 1);
    for (int k = threadIdx.x; k < Tz - 1; k += 256) outseq[k] = ys[k];
}

extern "C" void kernel_launch(void* const* d_in, const int* in_sizes, int n_in,
                              void* d_out, int out_size, void* d_ws, size_t ws_size,
                              hipStream_t stream) {
    const float* logits = (const float*)d_in[0];
    const float* masks  = (const float*)d_in[1];
    const float* trans  = (const float*)d_in[2];
    float* out = (float*)d_out;
    (void)in_sizes; (void)n_in; (void)out_size; (void)d_ws; (void)ws_size;

    crf_viterbi_kernel<<<dim3(Bz), dim3(256), 0, stream>>>(logits, masks, trans, out);
}

// Round 4
// 352.762 us; speedup vs baseline: 1.7927x; 1.1744x over previous
//
#include <hip/hip_runtime.h>

// CRF Viterbi decode (B=512, T=512, S=64).
// R3: 8 waves per block (512 thr), one batch per block. fv lives in LDS only:
// each wave broadcast-reads its 8-prev slice (2 uniform ds_read_b128), forms
// 8 scores, reduces with a max3 tree (exact max) + first-index equality scan
// (exact jnp first-argmax), publishes {val,idx} as one ds_write_b64.
// One responsible wave per 4-step group merges the 8 partials, writes the new
// fv vector and packs backpointers; two barriers/step. Backpointers packed
// 4 tags/dword in LDS (32 KB). Backtrace: wave 0 readlane chain (validated).
// Output: out[0..B) = path_score, out[B + b*(T-1) + t] = (float)tag.

constexpr int Bz = 512;
constexpr int Tz = 512;
constexpr int Sz = 64;
constexpr float NEGINF = -10000.0f;

__global__ __launch_bounds__(512)
void crf_viterbi_kernel(const float* __restrict__ logits,
                        const float* __restrict__ masks,
                        const float* __restrict__ trans,
                        float* __restrict__ out)
{
    const int n = threadIdx.x & 63;   // next-tag index / lane id
    const int w = threadIdx.x >> 6;   // wave id 0..7, owns prevs [8w, 8w+8)
    const int b = blockIdx.x;

    __shared__ unsigned bp[128 * 64];   // packed backpointers, 32 KB
    __shared__ int2 pvi[8][64];         // per-wave partial {val bits, local idx}
    __shared__ float fvs[64];           // the forward vector
    __shared__ float ys[Tz - 1];        // emitted tags (backtrace)

    // transitions slice: tr[j] = trans[n][8w + j]
    float tr[8];
    {
        const float4* tr4 = reinterpret_cast<const float4*>(trans + n * 64 + 8 * w);
        float4 t0 = tr4[0], t1 = tr4[1];
        tr[0] = t0.x; tr[1] = t0.y; tr[2] = t0.z; tr[3] = t0.w;
        tr[4] = t1.x; tr[5] = t1.y; tr[6] = t1.z; tr[7] = t1.w;
    }

    if (threadIdx.x < 64) fvs[n] = (n == 0) ? 0.0f : NEGINF;

    const float* lgbase = logits + (size_t)b * Tz * Sz;
    const float* mkbase = masks + (size_t)b * Tz;

    float lg0 = lgbase[1 * Sz + n];     // emission for step 0 (t=1)
    float lg1 = lgbase[2 * Sz + n];     // emission for step 1 (t=2)
    unsigned pk = 0;
    float psc = 0.0f;

    __syncthreads();

    #pragma unroll 4
    for (int i = 0; i < Tz - 1; ++i) {
        // uniform broadcast read of this wave's fv slice (2 x ds_read_b128)
        const float4* fv4 = reinterpret_cast<const float4*>(&fvs[8 * w]);
        float4 f0 = fv4[0], f1 = fv4[1];

        float v[8];
        v[0] = f0.x + tr[0]; v[1] = f0.y + tr[1];
        v[2] = f0.z + tr[2]; v[3] = f0.w + tr[3];
        v[4] = f1.x + tr[4]; v[5] = f1.y + tr[5];
        v[6] = f1.z + tr[6]; v[7] = f1.w + tr[7];

        // exact max via balanced tree (v_max3), then first-index equality scan
        float m01 = fmaxf(v[0], v[1]), m23 = fmaxf(v[2], v[3]);
        float m45 = fmaxf(v[4], v[5]), m67 = fmaxf(v[6], v[7]);
        float lm  = fmaxf(fmaxf(m01, m23), fmaxf(m45, m67));

        int li = 7;
        #pragma unroll
        for (int j = 6; j >= 0; --j) li = (v[j] == lm) ? j : li;

        pvi[w][n] = make_int2(__float_as_int(lm), li);
        __syncthreads();                       // barrier A: partials visible

        const int grp = i >> 2;
        if (w == (grp & 7)) {                  // responsible wave (uniform branch)
            float cv[8]; int ci[8];
            #pragma unroll
            for (int q = 0; q < 8; ++q) {
                int2 p = pvi[q][n];
                cv[q] = __int_as_float(p.x);
                ci[q] = 8 * q + p.y;
            }
            float a01 = fmaxf(cv[0], cv[1]), a23 = fmaxf(cv[2], cv[3]);
            float a45 = fmaxf(cv[4], cv[5]), a67 = fmaxf(cv[6], cv[7]);
            float m   = fmaxf(fmaxf(a01, a23), fmaxf(a45, a67));

            int gi = ci[7];
            #pragma unroll
            for (int q = 6; q >= 0; --q) gi = (cv[q] == m) ? ci[q] : gi;

            if (i == Tz - 2) psc = m;          // vmaxs[-1] pre-feat (wave 7 owns)

            pk |= ((unsigned)gi) << (8 * (i & 3));
            if ((i & 3) == 3) { bp[grp * 64 + n] = pk; pk = 0; }

            float mk = mkbase[i + 1];          // uniform -> s_load
            fvs[n] = m + lg0 * mk;             // mask multiplies emission only
        }
        __syncthreads();                       // barrier B: new fv visible

        lg0 = lg1;                             // rotate emission prefetch
        int t3 = (i + 3 < Tz) ? (i + 3) : (Tz - 1);
        lg1 = lgbase[t3 * Sz + n];
    }

    if (w == 7) {
        bp[127 * 64 + n] = pk;                 // flush steps 508..510 (resp of grp 127)
        if (n == 63) out[b] = psc;             // path_score = vmaxs[-1][:,63]
    }

    __syncthreads();

    // --- backtrace (wave 0 only; validated readlane chain) ---
    if (w == 0) {
        unsigned wcur = bp[127 * 64 + n];
        int w127_63 = __builtin_amdgcn_readlane((int)wcur, 63);
        int tag = (w127_63 >> 16) & 255;       // t0 = bptrs[510][63]

        for (int g = 127; g >= 0; --g) {
            unsigned wnext = (g > 0) ? bp[(g - 1) * 64 + n] : 0u;  // prefetch
            int smax = (g == 127) ? 2 : 3;
            for (int s = smax; s >= 0; --s) {
                int idx = 4 * g + s;
                if (n == 0) ys[idx] = (float)tag;   // emit BEFORE following ptr
                int wd = __builtin_amdgcn_readlane((int)wcur, tag);
                tag = (wd >> (8 * s)) & 255;
            }
            wcur = wnext;
        }
    }

    __syncthreads();

    float* outseq = out + Bz + (size_t)b * (Tz - 1);
    for (int k = threadIdx.x; k < Tz - 1; k += 512) outseq[k] = ys[k];
}

extern "C" void kernel_launch(void* const* d_in, const int* in_sizes, int n_in,
                              void* d_out, int out_size, void* d_ws, size_t ws_size,
                              hipStream_t stream) {
    const float* logits = (const float*)d_in[0];
    const float* masks  = (const float*)d_in[1];
    const float* trans  = (const float*)d_in[2];
    float* out = (float*)d_out;
    (void)in_sizes; (void)n_in; (void)out_size; (void)d_ws; (void)ws_size;

    crf_viterbi_kernel<<<dim3(Bz), dim3(512), 0, stream>>>(logits, masks, trans, out);
}